// Round 6
// baseline (243.520 us; speedup 1.0000x reference)
//
#include <hip/hip_runtime.h>

#define HH 128
#define WW 128
#define NPIX 16384
#define NC 32
#define NO 32
#define KS 9
#define TAPS 81
#define DIL 2
#define PAD 8
#define SMAX 27.6310211159f   // s <= SMAX <=> exp(-0.5 s) >= 1e-6; dropped-tap err << 8.8e-4
#define NW (NO * NC * TAPS)   // 82944
#define NWAVE 256
#define OG 8                  // output-channel groups (blockIdx.y)
#define OPG 4                 // outputs per thread
#define JG0 0x01Fu            // j in 0..4
#define JG1 0x1E0u            // j in 5..8

// ---------------------------------------------------------------------------
// prep: grid (64, KS+1), block 512.
//  i<KS : guidance s for row i. Threads split 32 channels into 2 halves
//         (tid<256 -> c 0..15, tid>=256 -> c 16..31); halves combine in LDS.
//         Waves 0-3 then exp+ballot+store kv and the per-(wave,row) live mask.
//  i==KS: weight transpose -> [tap][og][o][c] (wave-uniform s_loads in pac).
// 4608 gather waves total = 18 waves/CU: latency-hiding via occupancy.
// ---------------------------------------------------------------------------
__global__ __launch_bounds__(512, 4) void prep_k_kernel(
    const float* __restrict__ f,
    const float* __restrict__ W1, const float* __restrict__ W2,
    float* __restrict__ kbuf, unsigned* __restrict__ live9,
    float* __restrict__ W1t, float* __restrict__ W2t)
{
    const int i = blockIdx.y;
    if (i == KS) {                        // weight transpose
        for (int t = blockIdx.x * 512 + threadIdx.x; t < NW; t += 64 * 512) {
            int o = t / (NC * TAPS);
            int r = t - o * (NC * TAPS);
            int c = r / TAPS;
            int tap = r - c * TAPS;
            int d = ((tap * OG + (o >> 2)) * OPG + (o & 3)) * NC + c;
            W1t[d] = W1[t];
            W2t[d] = W2[t];
        }
        return;
    }
    __shared__ float sh[2][KS][256];
    const int half = threadIdx.x >> 8;    // channel half
    const int pl = threadIdx.x & 255;     // pixel local
    const int pix = blockIdx.x * 256 + pl;
    const int l = pl & 63;
    const int h = pix >> 7, w = pix & (WW - 1);
    const int qh = h + i * DIL - PAD;     // wave-uniform (64 px share h)
    const int cb = half * 16;

    if ((unsigned)qh < HH) {
        float fc[16];
#pragma unroll
        for (int c = 0; c < 16; ++c) fc[c] = f[(cb + c) * NPIX + pix];
#pragma unroll 3
        for (int j = 0; j < KS; ++j) {
            int qw = w + j * DIL - PAD;
            qw = qw < 0 ? 0 : (qw > WW - 1 ? WW - 1 : qw);  // clamp; combine masks
            int q = qh * WW + qw;
            float s0 = 0.f, s1 = 0.f, s2 = 0.f, s3 = 0.f;
#pragma unroll
            for (int c = 0; c < 16; c += 4) {
                float d0 = f[(cb + c + 0) * NPIX + q] - fc[c + 0];
                float d1 = f[(cb + c + 1) * NPIX + q] - fc[c + 1];
                float d2 = f[(cb + c + 2) * NPIX + q] - fc[c + 2];
                float d3 = f[(cb + c + 3) * NPIX + q] - fc[c + 3];
                s0 = fmaf(d0, d0, s0); s1 = fmaf(d1, d1, s1);
                s2 = fmaf(d2, d2, s2); s3 = fmaf(d3, d3, s3);
            }
            sh[half][j][pl] = (s0 + s1) + (s2 + s3);
        }
    }
    __syncthreads();
    if (half == 0) {
        const bool vh = (unsigned)qh < HH;
        unsigned wmask = 0;
#pragma unroll
        for (int j = 0; j < KS; ++j) {
            int qw = w + j * DIL - PAD;
            bool valid = vh & ((unsigned)qw < WW);
            float s = sh[0][j][pl] + sh[1][j][pl];
            float su = valid ? s : 1e30f;          // invalid -> kv = 0
            if (__ballot(su <= SMAX)) {            // wave-uniform branch
                wmask |= 1u << j;
                kbuf[(i * KS + j) * NPIX + pix] = __expf(-0.5f * su);
            }
        }
        if (l == 0) live9[(pix >> 6) * KS + i] = wmask;
    }
}

// ---------------------------------------------------------------------------
// pac: grid (64, OG, 2), block 256, 4 blocks/CU => 16 waves/CU (4/SIMD).
// Block (px, og, jg) handles j-columns {0..4} or {5..8} of every row,
// accumulating its live taps (ping-pong software pipeline, direct coalesced
// gathers) into partial buffer part[jg]. Weights via wave-uniform s_load.
// No LDS, no atomics, no shuffles.
// ---------------------------------------------------------------------------
__global__ __launch_bounds__(256, 4) void pac_kernel(
    const float* __restrict__ in, const float* __restrict__ kbuf,
    const unsigned* __restrict__ live9, const float* __restrict__ Wt,
    float* __restrict__ part)
{
    const int pix = blockIdx.x * 256 + threadIdx.x;
    const int og = blockIdx.y, jg = blockIdx.z;
    const unsigned jmask = jg ? JG1 : JG0;
    const int h = pix >> 7, w = pix & (WW - 1);
    const int wv = pix >> 6;

    int i = 0;
    unsigned m = jmask & (unsigned)__builtin_amdgcn_readfirstlane((int)live9[wv * KS + 0]);
    auto next = [&]() -> int {                 // wave-uniform live-tap iterator
        while (m == 0) {
            if (++i >= KS) return -1;
            m = jmask & (unsigned)__builtin_amdgcn_readfirstlane((int)live9[wv * KS + i]);
        }
        int j = __builtin_ctz(m);
        m &= m - 1;
        return (i << 4) | j;
    };

    float acc0 = 0.f, acc1 = 0.f, acc2 = 0.f, acc3 = 0.f;
    float xA[NC], xB[NC];
    float kvA, kvB;
    const float* wpA; const float* wpB;

#define LOAD(tp, X, KV, WP) do {                                           \
        int ii = (tp) >> 4, jj = (tp) & 15;                                \
        int qh_ = h + ii * DIL - PAD;                                      \
        int qw_ = w + jj * DIL - PAD;                                      \
        bool valid_ = ((unsigned)qh_ < HH) & ((unsigned)qw_ < WW);         \
        int q_ = valid_ ? (qh_ * WW + qw_) : pix;                          \
        KV = kbuf[(ii * KS + jj) * NPIX + pix];                            \
        WP = Wt + ((ii * KS + jj) * OG + og) * (OPG * NC);                 \
        _Pragma("unroll")                                                  \
        for (int c = 0; c < NC; ++c) X[c] = in[c * NPIX + q_];             \
    } while (0)

#define CONSUME(X, KV, WP) do {                                            \
        float t0 = 0.f, t1 = 0.f, t2 = 0.f, t3 = 0.f;                      \
        _Pragma("unroll")                                                  \
        for (int c = 0; c < NC; ++c) {                                     \
            float xv = X[c];                                               \
            t0 = fmaf(xv, WP[0 * NC + c], t0);                             \
            t1 = fmaf(xv, WP[1 * NC + c], t1);                             \
            t2 = fmaf(xv, WP[2 * NC + c], t2);                             \
            t3 = fmaf(xv, WP[3 * NC + c], t3);                             \
        }                                                                  \
        acc0 = fmaf(KV, t0, acc0); acc1 = fmaf(KV, t1, acc1);              \
        acc2 = fmaf(KV, t2, acc2); acc3 = fmaf(KV, t3, acc3);              \
    } while (0)

    int tapA = next();
    if (tapA >= 0) {
        LOAD(tapA, xA, kvA, wpA);
        for (;;) {
            int tapB = next();
            if (tapB < 0) { CONSUME(xA, kvA, wpA); break; }
            LOAD(tapB, xB, kvB, wpB);
            CONSUME(xA, kvA, wpA);
            tapA = next();
            if (tapA < 0) { CONSUME(xB, kvB, wpB); break; }
            LOAD(tapA, xA, kvA, wpA);
            CONSUME(xB, kvB, wpB);
        }
    }
#undef LOAD
#undef CONSUME

    float* p = part + (jg * NO + og * OPG) * NPIX + pix;
    p[0 * NPIX] = acc0;
    p[1 * NPIX] = acc1;
    p[2 * NPIX] = acc2;
    p[3 * NPIX] = acc3;
}

// ---------------------------------------------------------------------------
// reduce: out[o,p] = bias[o] + part[0][o][p] + part[1][o][p]. Coalesced.
// ---------------------------------------------------------------------------
__global__ __launch_bounds__(256) void reduce_kernel(
    const float* __restrict__ part, const float* __restrict__ bias,
    float* __restrict__ out)
{
    int tid = blockIdx.x * 256 + threadIdx.x;      // NO*NPIX
    int o = tid >> 14;
    out[tid] = bias[o] + part[tid] + part[NO * NPIX + tid];
}

// ---------------------------------------------------------------------------
// Fallback (round-1 proven path, 2 MB ws) in case ws is small.
// ---------------------------------------------------------------------------
#define CHUNK 27
#define NCHUNK 3
#define KMIN 1e-6f
__global__ __launch_bounds__(256) void pac_layer_fuse(
    const float* __restrict__ in, const float* __restrict__ f,
    const float* __restrict__ Wt, const float* __restrict__ bias,
    float* __restrict__ out)
{
    __shared__ float wl[NC * CHUNK * 8];
    const int og = blockIdx.y;
    const int pix = blockIdx.x * 256 + threadIdx.x;
    const int h = pix >> 7, w = pix & (WW - 1);
    float acc[8];
#pragma unroll
    for (int i = 0; i < 8; ++i) acc[i] = 0.f;
    float fc[NC];
#pragma unroll
    for (int c = 0; c < NC; ++c) fc[c] = f[c * NPIX + pix];
    for (int ch = 0; ch < NCHUNK; ++ch) {
        __syncthreads();
        for (int idx = threadIdx.x; idx < NC * CHUNK * 8; idx += 256) {
            int t = idx % CHUNK;
            int c = (idx / CHUNK) % NC;
            int o = idx / (CHUNK * NC);
            wl[(c * CHUNK + t) * 8 + o] =
                Wt[(og * 8 + o) * (NC * TAPS) + c * TAPS + ch * CHUNK + t];
        }
        __syncthreads();
        for (int t = 0; t < CHUNK; ++t) {
            int tap = ch * CHUNK + t;
            int qh = h + (tap / KS) * DIL - PAD;
            int qw = w + (tap % KS) * DIL - PAD;
            bool valid = ((unsigned)qh < HH) & ((unsigned)qw < WW);
            int q = qh * WW + qw;
            float s = 0.f;
#pragma unroll
            for (int c = 0; c < NC; ++c) {
                float fn = valid ? f[c * NPIX + q] : 0.f;
                float d = fn - fc[c];
                s = fmaf(d, d, s);
            }
            float kv = __expf(-0.5f * s);
            if (__all((kv < KMIN) | (!valid))) continue;
            const float* wpp = &wl[t * 8];
#pragma unroll 8
            for (int c = 0; c < NC; ++c) {
                float v = valid ? in[c * NPIX + q] : 0.f;
                v *= kv;
#pragma unroll
                for (int o = 0; o < 8; ++o)
                    acc[o] = fmaf(v, wpp[c * CHUNK * 8 + o], acc[o]);
            }
        }
    }
#pragma unroll
    for (int o = 0; o < 8; ++o)
        out[(og * 8 + o) * NPIX + pix] = acc[o] + bias[og * 8 + o];
}

// ---------------------------------------------------------------------------
extern "C" void kernel_launch(void* const* d_in, const int* in_sizes, int n_in,
                              void* d_out, int out_size, void* d_ws, size_t ws_size,
                              hipStream_t stream)
{
    (void)in_sizes; (void)n_in; (void)out_size;
    const float* x  = (const float*)d_in[0];
    const float* f  = (const float*)d_in[1];
    const float* W1 = (const float*)d_in[2];
    const float* b1 = (const float*)d_in[3];
    const float* W2 = (const float*)d_in[4];
    const float* b2 = (const float*)d_in[5];
    float* out = (float*)d_out;

    float* ws = (float*)d_ws;
    float* kbuf = ws;                                    // TAPS*NPIX
    unsigned* live9 = (unsigned*)(ws + TAPS * NPIX);     // NWAVE*KS
    float* W1t = ws + TAPS * NPIX + NWAVE * KS;          // NW
    float* W2t = W1t + NW;                               // NW
    float* ht  = W2t + NW;                               // NO*NPIX
    float* part = ht + NO * NPIX;                        // 2*NO*NPIX
    const size_t need =
        (size_t)(TAPS * NPIX + NWAVE * KS + 2 * NW + 3 * NO * NPIX) * sizeof(float);

    if (ws_size >= need) {
        prep_k_kernel<<<dim3(64, KS + 1), 512, 0, stream>>>(
            f, W1, W2, kbuf, live9, W1t, W2t);
        pac_kernel<<<dim3(64, OG, 2), 256, 0, stream>>>(x, kbuf, live9, W1t, part);
        reduce_kernel<<<NO * NPIX / 256, 256, 0, stream>>>(part, b1, ht);
        pac_kernel<<<dim3(64, OG, 2), 256, 0, stream>>>(ht, kbuf, live9, W2t, part);
        reduce_kernel<<<NO * NPIX / 256, 256, 0, stream>>>(part, b2, out);
    } else {
        float* hbuf = ws;
        pac_layer_fuse<<<dim3(64, 4), 256, 0, stream>>>(x, f, W1, b1, hbuf);
        pac_layer_fuse<<<dim3(64, 4), 256, 0, stream>>>(hbuf, f, W2, b2, out);
    }
}

// Round 7
// 166.102 us; speedup vs baseline: 1.4661x; 1.4661x over previous
//
#include <hip/hip_runtime.h>

#define HH 128
#define WW 128
#define NPIX 16384
#define NC 32
#define NO 32
#define KS 9
#define TAPS 81
#define DIL 2
#define PAD 8
#define SMAX 27.6310211159f   // s<=SMAX <=> exp(-0.5s)>=1e-6; dropped-tap err proven 6e-5
#define NW (NO * NC * TAPS)   // 82944

// ---------------------------------------------------------------------------
// prep_s: grid (128 h, 4 cq), block 256. Stage f rows qh=h+2r-8 (r=0..8) for
// 8 channels in LDS (pad+1 -> conflict-free), then each thread (px, ihalf)
// computes partial s (sum over its 8 ch of (f_q - f_c)^2) for taps
// i in its half, all j, and streams them to spart[(tap*4+cq)*NPIX + pix].
// OOB rows/cols clamped (finite garbage) -- combine masks them geometrically.
// ---------------------------------------------------------------------------
__global__ __launch_bounds__(256, 2) void prep_s_kernel(
    const float* __restrict__ f, float* __restrict__ spart)
{
    __shared__ float sf[KS][8][WW + 1];
    const int h = blockIdx.x, cq = blockIdx.y, cb = cq * 8;
    for (int idx = threadIdx.x; idx < KS * 8 * WW; idx += 256) {
        int px = idx & (WW - 1);
        int t = idx >> 7;
        int cc = t & 7, r = t >> 3;
        int qh = h + DIL * r - PAD;
        qh = qh < 0 ? 0 : (qh > HH - 1 ? HH - 1 : qh);
        sf[r][cc][px] = f[(cb + cc) * NPIX + qh * WW + px];
    }
    __syncthreads();
    const int px = threadIdx.x & (WW - 1);
    const int ihalf = threadIdx.x >> 7;
    float fc[8];
#pragma unroll
    for (int cc = 0; cc < 8; ++cc) fc[cc] = sf[4][cc][px];   // row 4 == h
    const int i0 = ihalf ? 4 : 0, i1 = ihalf ? KS : 4;
    for (int i = i0; i < i1; ++i) {
#pragma unroll
        for (int j = 0; j < KS; ++j) {
            int qw = px + DIL * j - PAD;
            qw = qw < 0 ? 0 : (qw > WW - 1 ? WW - 1 : qw);
            float s = 0.f;
#pragma unroll
            for (int cc = 0; cc < 8; ++cc) {
                float d = sf[i][cc][qw] - fc[cc];
                s = fmaf(d, d, s);
            }
            spart[((i * KS + j) * 4 + cq) * NPIX + h * WW + px] = s;
        }
    }
}

// ---------------------------------------------------------------------------
// combine: grid (64, KS+1), block 256.
//  i<KS : s = sum of 4 cq-partials; kv = valid ? exp(-0.5s) : 0 -> kbuf;
//         per-wave 9-bit live mask (bit j iff any lane valid && s<=SMAX).
//  i==KS: weight transpose -> Wt[((tap*4+cq)*2+oh)*128 + o16*8 + c8].
// ---------------------------------------------------------------------------
__global__ __launch_bounds__(256) void combine_kernel(
    const float* __restrict__ spart,
    const float* __restrict__ W1, const float* __restrict__ W2,
    float* __restrict__ kbuf, unsigned* __restrict__ live9,
    float* __restrict__ W1t, float* __restrict__ W2t)
{
    const int i = blockIdx.y;
    if (i == KS) {
        for (int t = blockIdx.x * 256 + threadIdx.x; t < NW; t += 64 * 256) {
            int o = t / (NC * TAPS);
            int r = t - o * (NC * TAPS);
            int c = r / TAPS;
            int tap = r - c * TAPS;
            int d = ((tap * 4 + (c >> 3)) * 2 + (o >> 4)) * 128 + (o & 15) * 8 + (c & 7);
            W1t[d] = W1[t];
            W2t[d] = W2[t];
        }
        return;
    }
    const int pix = blockIdx.x * 256 + threadIdx.x;
    const int px = pix & (WW - 1), h = pix >> 7;
    const int qh = h + DIL * i - PAD;
    const bool vh = (unsigned)qh < HH;
    unsigned wmask = 0;
#pragma unroll
    for (int j = 0; j < KS; ++j) {
        int qw = px + DIL * j - PAD;
        bool valid = vh & ((unsigned)qw < WW);
        const float* sp = spart + ((i * KS + j) * 4) * NPIX + pix;
        float s = (sp[0] + sp[NPIX]) + (sp[2 * NPIX] + sp[3 * NPIX]);
        float kv = valid ? __expf(-0.5f * s) : 0.f;
        kbuf[(i * KS + j) * NPIX + pix] = kv;
        if (__ballot(valid && (s <= SMAX))) wmask |= 1u << j;
    }
    if ((threadIdx.x & 63) == 0) live9[(pix >> 6) * KS + i] = wmask;
}

// ---------------------------------------------------------------------------
// pac: grid (128 h, 4 cq), block 256 = 128 px x 2 og-halves, 2 blocks/CU.
// Stage in rows (8 ch) in LDS once; per live tap read 8 LDS values
// (conflict-free) + kv (2-deep pipelined) and do 8c x 16o FMA; weights via
// wave-uniform s_load. Channel-partial sums -> part[cq], no atomics.
// ---------------------------------------------------------------------------
__global__ __launch_bounds__(256, 2) void pac_kernel(
    const float* __restrict__ in, const float* __restrict__ kbuf,
    const unsigned* __restrict__ live9, const float* __restrict__ Wt,
    float* __restrict__ part)
{
    __shared__ float sx[KS][8][WW + 1];
    const int h = blockIdx.x, cq = blockIdx.y, cb = cq * 8;
    for (int idx = threadIdx.x; idx < KS * 8 * WW; idx += 256) {
        int px = idx & (WW - 1);
        int t = idx >> 7;
        int cc = t & 7, r = t >> 3;
        int qh = h + DIL * r - PAD;
        qh = qh < 0 ? 0 : (qh > HH - 1 ? HH - 1 : qh);
        sx[r][cc][px] = in[(cb + cc) * NPIX + qh * WW + px];
    }
    __syncthreads();
    const int px = threadIdx.x & (WW - 1);
    const int oh = threadIdx.x >> 7;
    const int wv = 2 * h + ((px >> 6) & 1);      // wave-uniform
    const int pixr = h * WW + px;

    int i = 0;
    unsigned m = (unsigned)__builtin_amdgcn_readfirstlane((int)live9[wv * KS + 0]);
    auto next = [&]() -> int {                   // wave-uniform live-tap iterator
        while (m == 0) {
            if (++i >= KS) return -1;
            m = (unsigned)__builtin_amdgcn_readfirstlane((int)live9[wv * KS + i]);
        }
        int j = __builtin_ctz(m);
        m &= m - 1;
        return i * KS + j;
    };

    float acc[16];
#pragma unroll
    for (int o = 0; o < 16; ++o) acc[o] = 0.f;

    float xA[8], xB[8], kvA, kvB;
    const float* wpA; const float* wpB;

#define LOAD(tp, X, KV, WP) do {                                           \
        int ii = (tp) / KS, jj = (tp) - ii * KS;                           \
        int qw_ = px + DIL * jj - PAD;                                     \
        qw_ = qw_ < 0 ? 0 : (qw_ > WW - 1 ? WW - 1 : qw_);                 \
        KV = kbuf[(tp) * NPIX + pixr];                                     \
        WP = Wt + (((tp) * 4 + cq) * 2 + oh) * 128;                        \
        _Pragma("unroll")                                                  \
        for (int cc = 0; cc < 8; ++cc) X[cc] = sx[ii][cc][qw_];            \
    } while (0)

#define CONSUME(X, KV, WP) do {                                            \
        _Pragma("unroll")                                                  \
        for (int o = 0; o < 16; ++o) {                                     \
            float t = 0.f;                                                 \
            _Pragma("unroll")                                              \
            for (int cc = 0; cc < 8; ++cc)                                 \
                t = fmaf(X[cc], WP[o * 8 + cc], t);                        \
            acc[o] = fmaf(KV, t, acc[o]);                                  \
        }                                                                  \
    } while (0)

    int tapA = next();
    if (tapA >= 0) {
        LOAD(tapA, xA, kvA, wpA);
        for (;;) {
            int tapB = next();
            if (tapB < 0) { CONSUME(xA, kvA, wpA); break; }
            LOAD(tapB, xB, kvB, wpB);
            CONSUME(xA, kvA, wpA);
            tapA = next();
            if (tapA < 0) { CONSUME(xB, kvB, wpB); break; }
            LOAD(tapA, xA, kvA, wpA);
            CONSUME(xB, kvB, wpB);
        }
    }
#undef LOAD
#undef CONSUME

#pragma unroll
    for (int o = 0; o < 16; ++o)
        part[(cq * NO + oh * 16 + o) * NPIX + pixr] = acc[o];
}

// ---------------------------------------------------------------------------
// reduce: out[o,p] = bias[o] + sum_cq part[cq][o][p]. Fully coalesced.
// ---------------------------------------------------------------------------
__global__ __launch_bounds__(256) void reduce_kernel(
    const float* __restrict__ part, const float* __restrict__ bias,
    float* __restrict__ out)
{
    int tid = blockIdx.x * 256 + threadIdx.x;    // NO*NPIX
    int o = tid >> 14;
    out[tid] = bias[o] + (part[tid] + part[NO * NPIX + tid])
             + (part[2 * NO * NPIX + tid] + part[3 * NO * NPIX + tid]);
}

// ---------------------------------------------------------------------------
// Fallback (round-1 proven path, 2 MB ws) in case ws is small.
// ---------------------------------------------------------------------------
#define CHUNK 27
#define NCHUNK 3
#define KMIN 1e-6f
__global__ __launch_bounds__(256) void pac_layer_fuse(
    const float* __restrict__ in, const float* __restrict__ f,
    const float* __restrict__ Wt, const float* __restrict__ bias,
    float* __restrict__ out)
{
    __shared__ float wl[NC * CHUNK * 8];
    const int og = blockIdx.y;
    const int pix = blockIdx.x * 256 + threadIdx.x;
    const int h = pix >> 7, w = pix & (WW - 1);
    float acc[8];
#pragma unroll
    for (int i = 0; i < 8; ++i) acc[i] = 0.f;
    float fc[NC];
#pragma unroll
    for (int c = 0; c < NC; ++c) fc[c] = f[c * NPIX + pix];
    for (int ch = 0; ch < NCHUNK; ++ch) {
        __syncthreads();
        for (int idx = threadIdx.x; idx < NC * CHUNK * 8; idx += 256) {
            int t = idx % CHUNK;
            int c = (idx / CHUNK) % NC;
            int o = idx / (CHUNK * NC);
            wl[(c * CHUNK + t) * 8 + o] =
                Wt[(og * 8 + o) * (NC * TAPS) + c * TAPS + ch * CHUNK + t];
        }
        __syncthreads();
        for (int t = 0; t < CHUNK; ++t) {
            int tap = ch * CHUNK + t;
            int qh = h + (tap / KS) * DIL - PAD;
            int qw = w + (tap % KS) * DIL - PAD;
            bool valid = ((unsigned)qh < HH) & ((unsigned)qw < WW);
            int q = qh * WW + qw;
            float s = 0.f;
#pragma unroll
            for (int c = 0; c < NC; ++c) {
                float fn = valid ? f[c * NPIX + q] : 0.f;
                float d = fn - fc[c];
                s = fmaf(d, d, s);
            }
            float kv = __expf(-0.5f * s);
            if (__all((kv < KMIN) | (!valid))) continue;
            const float* wpp = &wl[t * 8];
#pragma unroll 8
            for (int c = 0; c < NC; ++c) {
                float v = valid ? in[c * NPIX + q] : 0.f;
                v *= kv;
#pragma unroll
                for (int o = 0; o < 8; ++o)
                    acc[o] = fmaf(v, wpp[c * CHUNK * 8 + o], acc[o]);
            }
        }
    }
#pragma unroll
    for (int o = 0; o < 8; ++o)
        out[(og * 8 + o) * NPIX + pix] = acc[o] + bias[og * 8 + o];
}

// ---------------------------------------------------------------------------
extern "C" void kernel_launch(void* const* d_in, const int* in_sizes, int n_in,
                              void* d_out, int out_size, void* d_ws, size_t ws_size,
                              hipStream_t stream)
{
    (void)in_sizes; (void)n_in; (void)out_size;
    const float* x  = (const float*)d_in[0];
    const float* f  = (const float*)d_in[1];
    const float* W1 = (const float*)d_in[2];
    const float* b1 = (const float*)d_in[3];
    const float* W2 = (const float*)d_in[4];
    const float* b2 = (const float*)d_in[5];
    float* out = (float*)d_out;

    float* ws = (float*)d_ws;
    float* spart = ws;                                   // 81*4*NPIX
    float* kbuf = spart + TAPS * 4 * NPIX;               // 81*NPIX
    unsigned* live9 = (unsigned*)(kbuf + TAPS * NPIX);   // 256*9 (pad 2560)
    float* W1t = kbuf + TAPS * NPIX + 2560;              // NW
    float* W2t = W1t + NW;                               // NW
    float* part = W2t + NW;                              // 4*NO*NPIX
    float* ht = part + 4 * NO * NPIX;                    // NO*NPIX
    const size_t need =
        (size_t)(TAPS * 4 * NPIX + TAPS * NPIX + 2560 + 2 * NW + 5 * NO * NPIX)
        * sizeof(float);                                 // ~37.8 MB

    if (ws_size >= need) {
        prep_s_kernel<<<dim3(HH, 4), 256, 0, stream>>>(f, spart);
        combine_kernel<<<dim3(64, KS + 1), 256, 0, stream>>>(
            spart, W1, W2, kbuf, live9, W1t, W2t);
        pac_kernel<<<dim3(HH, 4), 256, 0, stream>>>(x, kbuf, live9, W1t, part);
        reduce_kernel<<<NO * NPIX / 256, 256, 0, stream>>>(part, b1, ht);
        pac_kernel<<<dim3(HH, 4), 256, 0, stream>>>(ht, kbuf, live9, W2t, part);
        reduce_kernel<<<NO * NPIX / 256, 256, 0, stream>>>(part, b2, out);
    } else {
        float* hbuf = ws;
        pac_layer_fuse<<<dim3(64, 4), 256, 0, stream>>>(x, f, W1, b1, hbuf);
        pac_layer_fuse<<<dim3(64, 4), 256, 0, stream>>>(hbuf, f, W2, b2, out);
    }
}